// Round 6
// baseline (495.126 us; speedup 1.0000x reference)
//
#include <hip/hip_runtime.h>
#include <hip/hip_bf16.h>
#include <math.h>

#define TT 2048
#define NE 256
#define NHEAD 16

typedef __attribute__((ext_vector_type(8))) short bf16x8;
typedef __attribute__((ext_vector_type(4))) float f32x4;
typedef unsigned short ushort;
typedef __attribute__((ext_vector_type(8))) unsigned short us8;

__device__ __forceinline__ short f2bf(float x) {
  __hip_bfloat16 h = __float2bfloat16(x);
  return *reinterpret_cast<short*>(&h);
}
__device__ __forceinline__ float bf2f(ushort u) {
  unsigned v = ((unsigned)u) << 16;
  return __uint_as_float(v);
}
__device__ __forceinline__ unsigned pack2bf(float a, float b) {
  return (unsigned)(ushort)f2bf(a) | ((unsigned)(ushort)f2bf(b) << 16);
}

// ---------------- 1. logmap (+ x -> bf16 copy) ----------------
__global__ __launch_bounds__(256) void logmap_kernel(const float* __restrict__ x,
                                                     float* __restrict__ xh,
                                                     ushort* __restrict__ xbf) {
  __shared__ float red[16];
  int row = blockIdx.x, tid = threadIdx.x;
  int t = row & (TT - 1);
  float uv = x[row * NE + tid];
  float rv = (t == 0) ? 0.f : x[row * NE - NE + tid];
  xbf[row * NE + tid] = (ushort)f2bf(uv);
  // fused 3-way reduction: rv^2, uv^2, -rv*uv
  float a = rv * rv, bq = uv * uv, c2 = -rv * uv;
#pragma unroll
  for (int off = 32; off > 0; off >>= 1) {
    a += __shfl_down(a, off, 64);
    bq += __shfl_down(bq, off, 64);
    c2 += __shfl_down(c2, off, 64);
  }
  if ((tid & 63) == 0) {
    int w = tid >> 6;
    red[w] = a; red[4 + w] = bq; red[8 + w] = c2;
  }
  __syncthreads();
  float xn2 = red[0] + red[1] + red[2] + red[3];
  float un2 = red[4] + red[5] + red[6] + red[7];
  float ip  = red[8] + red[9] + red[10] + red[11];
  float den = 1.f + 2.f * ip + xn2 * un2;
  float mob = ((1.f + 2.f * ip + un2) * (-rv) + (1.f - xn2) * uv) / den;
  float m2 = mob * mob;
#pragma unroll
  for (int off = 32; off > 0; off >>= 1) m2 += __shfl_down(m2, off, 64);
  if ((tid & 63) == 0) red[12 + (tid >> 6)] = m2;
  __syncthreads();
  float an2 = red[12] + red[13] + red[14] + red[15];
  float an = sqrtf(an2);
  float cf = 1.f + xn2;
  float arg = fminf(sqrtf(an), 0.999f);
  xh[row * NE + tid] = cf * atanhf(arg) * mob / an;
}

// ---------------- 2. nq = rmsnorm(xh @ W_cq) -> bf16 ----------------
__global__ __launch_bounds__(128) void nq_kernel(const float* __restrict__ xh,
                                                 const float* __restrict__ W_cq,
                                                 const float* __restrict__ qnw,
                                                 ushort* __restrict__ nqb) {
  int row = blockIdx.x, tid = threadIdx.x;  // 128 thr
  __shared__ float xr[256];
  __shared__ float red[128];
  xr[tid] = xh[row * 256 + tid];
  xr[tid + 128] = xh[row * 256 + tid + 128];
  __syncthreads();
  float acc = 0.f;
  if (tid < 96) {
    const float* wp = W_cq + tid;
#pragma unroll 4
    for (int k = 0; k < 256; ++k) acc += xr[k] * wp[k * 96];
  }
  red[tid] = (tid < 96) ? acc * acc : 0.f;
  __syncthreads();
  for (int s = 64; s > 0; s >>= 1) {
    if (tid < s) red[tid] += red[tid + s];
    __syncthreads();
  }
  float sc = rsqrtf(red[0] / 96.f + 1e-6f);
  if (tid < 96) nqb[row * 96 + tid] = (ushort)f2bf(acc * sc * qnw[tid]);
}

// ---------------- 3. nkv(bf16) + imp scores + gate partials + kr ----------------
__global__ __launch_bounds__(128) void nkv_kernel(const float* __restrict__ x,
                                                  const float* __restrict__ W_ckv,
                                                  const float* __restrict__ kvnw,
                                                  const float* __restrict__ W_imp,
                                                  const float* __restrict__ b_imp,
                                                  const float* __restrict__ W_gate,
                                                  const float* __restrict__ W_kr,
                                                  ushort* __restrict__ nkvb,
                                                  float* __restrict__ scores,
                                                  float* __restrict__ gpart,
                                                  float* __restrict__ krtmp) {
  int row = blockIdx.x, tid = threadIdx.x;  // 128 thr
  __shared__ float xr[256];
  xr[tid] = x[row * 256 + tid];
  xr[tid + 128] = x[row * 256 + tid + 128];
  __syncthreads();
  const float* wp;
  int stride;
  if (tid < 32) { wp = W_ckv + tid; stride = 32; }
  else if (tid == 32) { wp = W_imp; stride = 1; }
  else if (tid < 36) { wp = W_gate + (tid - 33); stride = 3; }
  else if (tid < 100) { wp = W_kr + (tid - 36); stride = 64; }
  else { wp = W_ckv; stride = 0; }
  float acc = 0.f;
#pragma unroll 4
  for (int k = 0; k < 256; ++k) acc += xr[k] * wp[k * stride];
  float ss = acc * acc;
#pragma unroll
  for (int off = 16; off > 0; off >>= 1) ss += __shfl_xor(ss, off, 64);
  if (tid < 32) {
    float sc = rsqrtf(ss / 32.f + 1e-6f);
    nkvb[row * 32 + tid] = (ushort)f2bf(acc * sc * kvnw[tid]);
  } else if (tid == 32) {
    scores[row] = acc + b_imp[0];
  } else if (tid < 36) {
    gpart[row * 3 + (tid - 33)] = acc;
  } else if (tid < 100) {
    krtmp[row * 64 + (tid - 36)] = acc;
  }
}

// ---------------- merged weight convert (all 5 Wt buffers, 1 launch) ----------------
// Wt_q gets the 1/sqrt(96) attention scale folded in (commutes with RoPE).
__global__ __launch_bounds__(256) void wtconv_all_kernel(
    const float* __restrict__ W_dqn, const float* __restrict__ W_dqr,
    const float* __restrict__ W_dkn, const float* __restrict__ W_dv,
    const float* __restrict__ W_selk, const float* __restrict__ W_selv,
    const float* __restrict__ W_wink, const float* __restrict__ W_winv,
    const float* __restrict__ W_proj,
    ushort* __restrict__ Wt_q, ushort* __restrict__ Wt_kv,
    ushort* __restrict__ Wt_sel, ushort* __restrict__ Wt_win,
    ushort* __restrict__ Wt_proj) {
  int i = blockIdx.x * 256 + threadIdx.x;
  const float scale = 0.1020620726159658f;
  if (i < 147456) {  // Wt_q [1536][96]
    int n = i / 96, k = i - n * 96;
    float v = (n < 512) ? W_dqn[(size_t)k * 512 + n] : W_dqr[(size_t)k * 1024 + (n - 512)];
    Wt_q[i] = (ushort)f2bf(v * scale);
  } else if (i < 180224) {  // Wt_kv [1024][32]
    int j = i - 147456;
    int n = j / 32, k = j & 31;
    float v = (n < 512) ? W_dkn[(size_t)k * 512 + n] : W_dv[(size_t)k * 512 + (n - 512)];
    Wt_kv[j] = (ushort)f2bf(v);
  } else if (i < 704512) {  // Wt_sel [2048][256]
    int j = i - 180224;
    int n = j >> 8, k = j & 255;
    float v = (n < 1536) ? W_selk[(size_t)k * 1536 + n] : W_selv[(size_t)k * 512 + (n - 1536)];
    Wt_sel[j] = (ushort)f2bf(v);
  } else if (i < 1228800) {  // Wt_win [2048][256]
    int j = i - 704512;
    int n = j >> 8, k = j & 255;
    float v = (n < 1536) ? W_wink[(size_t)k * 1536 + n] : W_winv[(size_t)k * 512 + (n - 1536)];
    Wt_win[j] = (ushort)f2bf(v);
  } else if (i < 1359872) {  // Wt_proj [256][512]
    int j = i - 1228800;
    int n = j >> 9, k = j & 511;
    Wt_proj[j] = (ushort)f2bf(W_proj[(size_t)k * 256 + n]);
  }
}

// ---------------- bf16 MFMA GEMM: D[m][n] = sum_k A[m][k] * Wt[n][k] ----------------
__global__ __launch_bounds__(256) void gemm_kernel(const ushort* __restrict__ A,
                                                   const ushort* __restrict__ Bt,
                                                   void* __restrict__ Out,
                                                   const int* __restrict__ selidx,
                                                   int K, int ldo, int obf16) {
  __shared__ __align__(16) short As[128 * 40];
  __shared__ __align__(16) short Bs[128 * 40];
  int m0 = blockIdx.x * 128, n0 = blockIdx.y * 128;
  int tid = threadIdx.x;
  int wv = tid >> 6, lane = tid & 63;
  int l15 = lane & 15, quad = lane >> 4;
  int wm = wv >> 1, wn = wv & 1;

  int r = tid >> 1, seg = tid & 1;
  int arow = m0 + r;
  if (selidx) arow = ((arow >> 9) * TT) + selidx[m0 + r];
  const ushort* ga = A + (size_t)arow * K + seg * 16;
  const ushort* gb = Bt + (size_t)(n0 + r) * K + seg * 16;

  f32x4 acc[4][4];
#pragma unroll
  for (int i = 0; i < 4; ++i)
#pragma unroll
    for (int j = 0; j < 4; ++j) acc[i][j] = (f32x4){0.f, 0.f, 0.f, 0.f};

  int nk = K >> 5;
  us8 apre0 = *(const us8*)ga, apre1 = *(const us8*)(ga + 8);
  us8 bpre0 = *(const us8*)gb, bpre1 = *(const us8*)(gb + 8);
  for (int kk = 0; kk < nk; ++kk) {
    __syncthreads();
    *(us8*)(As + r * 40 + seg * 16) = apre0;
    *(us8*)(As + r * 40 + seg * 16 + 8) = apre1;
    *(us8*)(Bs + r * 40 + seg * 16) = bpre0;
    *(us8*)(Bs + r * 40 + seg * 16 + 8) = bpre1;
    __syncthreads();
    if (kk + 1 < nk) {
      apre0 = *(const us8*)(ga + (kk + 1) * 32);
      apre1 = *(const us8*)(ga + (kk + 1) * 32 + 8);
      bpre0 = *(const us8*)(gb + (kk + 1) * 32);
      bpre1 = *(const us8*)(gb + (kk + 1) * 32 + 8);
    }
    bf16x8 af[4], bf[4];
#pragma unroll
    for (int mf = 0; mf < 4; ++mf)
      af[mf] = *(const bf16x8*)(As + (wm * 64 + mf * 16 + l15) * 40 + quad * 8);
#pragma unroll
    for (int nf = 0; nf < 4; ++nf)
      bf[nf] = *(const bf16x8*)(Bs + (wn * 64 + nf * 16 + l15) * 40 + quad * 8);
#pragma unroll
    for (int mf = 0; mf < 4; ++mf)
#pragma unroll
      for (int nf = 0; nf < 4; ++nf)
        acc[mf][nf] = __builtin_amdgcn_mfma_f32_16x16x32_bf16(af[mf], bf[nf], acc[mf][nf], 0, 0, 0);
  }

#pragma unroll
  for (int mf = 0; mf < 4; ++mf) {
#pragma unroll
    for (int nf = 0; nf < 4; ++nf) {
#pragma unroll
      for (int reg = 0; reg < 4; ++reg) {
        int row = m0 + wm * 64 + mf * 16 + quad * 4 + reg;
        int col = n0 + wn * 64 + nf * 16 + l15;
        size_t oi = (size_t)row * ldo + col;
        float v = acc[mf][nf][reg];
        if (obf16) ((ushort*)Out)[oi] = (ushort)f2bf(v);
        else ((float*)Out)[oi] = v;
      }
    }
  }
}

// ---------------- rope: qbf (bf16, in place) + kr -> bf16 ----------------
__global__ __launch_bounds__(256) void rope_kernel(const float* __restrict__ cos_t,
                                                   const float* __restrict__ sin_t,
                                                   ushort* __restrict__ qbf,
                                                   const float* __restrict__ krtmp,
                                                   ushort* __restrict__ krbf) {
  int row = blockIdx.x, tid = threadIdx.x;
  int t = row & (TT - 1);
  for (int i = tid; i < 544; i += 256) {
    int dd = (i < 512) ? (i & 31) : (i - 512);
    float c = cos_t[t * 32 + dd], s = sin_t[t * 32 + dd];
    if (i < 512) {
      int h = i >> 5;
      ushort* p0 = qbf + (size_t)row * 1536 + 512 + h * 64 + dd;
      float xr = bf2f(p0[0]), xi = bf2f(p0[32]);
      p0[0] = (ushort)f2bf(xr * c - xi * s);
      p0[32] = (ushort)f2bf(xr * s + xi * c);
    } else {
      const float* p0 = krtmp + (size_t)row * 64 + dd;
      float xr = p0[0], xi = p0[32];
      krbf[(size_t)row * 64 + dd] = (ushort)f2bf(xr * c - xi * s);
      krbf[(size_t)row * 64 + dd + 32] = (ushort)f2bf(xr * s + xi * c);
    }
  }
}

// ---------------- gate finalize ----------------
__global__ __launch_bounds__(256) void gate_kernel(const float* __restrict__ gpart,
                                                   const float* __restrict__ b_gate,
                                                   float* __restrict__ bw) {
  int tid = threadIdx.x;  // 256
  float a0 = 0, a1 = 0, a2 = 0, a3 = 0, a4 = 0, a5 = 0;
  for (int r = tid; r < 2 * TT; r += 256) {
    float g0 = gpart[r * 3], g1 = gpart[r * 3 + 1], g2 = gpart[r * 3 + 2];
    if (r < TT) { a0 += g0; a1 += g1; a2 += g2; }
    else { a3 += g0; a4 += g1; a5 += g2; }
  }
  __shared__ float red[6][256];
  red[0][tid] = a0; red[1][tid] = a1; red[2][tid] = a2;
  red[3][tid] = a3; red[4][tid] = a4; red[5][tid] = a5;
  __syncthreads();
  for (int s = 128; s > 0; s >>= 1) {
    if (tid < s) {
#pragma unroll
      for (int q = 0; q < 6; ++q) red[q][tid] += red[q][tid + s];
    }
    __syncthreads();
  }
  if (tid == 0) {
    for (int b = 0; b < 2; ++b) {
      float v[3];
      float mx = -INFINITY;
      for (int j = 0; j < 3; ++j) {
        v[j] = red[b * 3 + j][0] / (float)TT + b_gate[j];
        mx = fmaxf(mx, v[j]);
      }
      float sum = 0.f;
      for (int j = 0; j < 3; ++j) { v[j] = expf(v[j] - mx); sum += v[j]; }
      for (int j = 0; j < 3; ++j) bw[b * 3 + j] = v[j] / sum;
    }
  }
}

// ---------------- top-k via rank counting + scan compaction ----------------
// rank_i = #{v_j > v_i} + #{v_j == v_i, j < i} (matches jax top_k tiebreak);
// selected iff rank < 512; output position = prefix of selected (ascending idx).
__global__ __launch_bounds__(1024) void topk_kernel(const float* __restrict__ scores,
                                                    int* __restrict__ selidx) {
  int b = blockIdx.x, tid = threadIdx.x;  // 1024 thr
  __shared__ unsigned sk[TT];
  __shared__ int pre[TT];
  for (int e = 0; e < 2; ++e) {
    int i = tid + e * 1024;
    float s = scores[b * TT + i];
    unsigned u = __float_as_uint(s);
    u = (u & 0x80000000u) ? ~u : (u | 0x80000000u);  // ascending-sortable
    sk[i] = u;
  }
  __syncthreads();
  int flag[2];
#pragma unroll
  for (int e = 0; e < 2; ++e) {
    int i = tid + e * 1024;
    unsigned u = sk[i];
    int r = 0;
    for (int j = 0; j < TT; ++j) {
      unsigned v = sk[j];
      r += (v > u) || (v == u && j < i);
    }
    flag[e] = (r < 512) ? 1 : 0;
    pre[i] = flag[e];
  }
  __syncthreads();
  for (int off = 1; off < TT; off <<= 1) {
    int a0 = (tid >= off) ? pre[tid - off] : 0;
    int a1 = (tid + 1024 >= off) ? pre[tid + 1024 - off] : 0;
    __syncthreads();
    pre[tid] += a0;
    pre[tid + 1024] += a1;
    __syncthreads();
  }
#pragma unroll
  for (int e = 0; e < 2; ++e) {
    int i = tid + e * 1024;
    if (flag[e]) selidx[b * 512 + pre[i] - 1] = i;
  }
}

// ---------------- fused MFMA flash attention (cmp + sel + win) ----------------
// Heavy-first schedule; no-max softmax; l via ones-MFMA; paired-b32 V commit.
__global__ __launch_bounds__(256) void flash_fused_kernel(
    const ushort* __restrict__ qbf,    // [row][qn 512 | qr 1024] bf16, scale folded
    const ushort* __restrict__ kv,     // [row][kn 512 | v 512] bf16
    const ushort* __restrict__ krbf,   // [row][64] bf16 (roped)
    const ushort* __restrict__ selt,   // [selrow][sk 1536 | sv 512] bf16
    const ushort* __restrict__ wint,   // [row][wk 1536 | wv 512] bf16
    const float* __restrict__ bw,
    ushort* __restrict__ attout) {     // [b*TT+t][h*32+d] bf16
  __shared__ __align__(16) short Qs[64 * 104];
  __shared__ __align__(16) short Ks[64 * 104];
  __shared__ __align__(16) short Vts[32 * 72];
  __shared__ __align__(16) short Ps[4 * 16 * 72];

  int bx = blockIdx.x;
  int qtile = 31 - (bx >> 5);  // heavy-first dispatch
  int bh = bx & 31;
  int b = bh >> 4, h = bh & 15;
  int tid = threadIdx.x;
  int wv = tid >> 6, lane = tid & 63;
  int l15 = lane & 15, quad = lane >> 4;
  const bf16x8 onesf = {16256, 16256, 16256, 16256, 16256, 16256, 16256, 16256};

  int qrow0 = qtile * 64;
  // ---- stage Q (64 x 96) bf16 copy ----
  for (int i = tid; i < 64 * 24; i += 256) {
    int qi = i / 24, dp = (i - qi * 24) * 4;
    int col = (dp < 32) ? (h * 32 + dp) : (512 + h * 64 + (dp - 32));
    ushort4 q4 = *(const ushort4*)(qbf + (size_t)(b * TT + qrow0 + qi) * 1536 + col);
    *(ushort4*)(Qs + qi * 104 + dp) = q4;
  }

  f32x4 oacc[2];
  oacc[0] = (f32x4){0.f, 0.f, 0.f, 0.f};
  oacc[1] = (f32x4){0.f, 0.f, 0.f, 0.f};

  ushort4 kpre[6];
  ushort2 vpa[2], vpb[2];

  for (int s = 0; s < 3; ++s) {
    const ushort *kb1, *kb2, *vb;
    size_t krs1, krs2, vrs;
    int split, Tk, causal;
    if (s == 0) {  // cmp
      kb1 = kv + h * 32;        krs1 = 1024; split = 32;
      kb2 = krbf;               krs2 = 64;
      vb = kv + 512 + h * 32;   vrs = 1024;
      Tk = TT; causal = 1;
    } else if (s == 1) {  // sel
      kb1 = selt + h * 96;      krs1 = 2048; split = 96;
      kb2 = selt;               krs2 = 2048;
      vb = selt + 1536 + h * 32; vrs = 2048;
      Tk = 512; causal = 0;
    } else {  // win
      kb1 = wint + h * 96;      krs1 = 2048; split = 96;
      kb2 = wint;               krs2 = 2048;
      vb = wint + 1536 + h * 32; vrs = 2048;
      Tk = TT; causal = 1;
    }
    size_t bTk = (size_t)b * Tk;

    auto prefetch = [&](int kt) {
      int krow0 = kt * 64;
#pragma unroll
      for (int c = 0; c < 6; ++c) {
        int i = c * 256 + tid;
        int kj = i / 24, dp = (i - kj * 24) * 4;
        const ushort* src = (dp < split)
                                ? kb1 + (bTk + krow0 + kj) * krs1 + dp
                                : kb2 + (bTk + krow0 + kj) * krs2 + (dp - split);
        kpre[c] = *(const ushort4*)src;
      }
      // V: row pairs, 2 shorts each -> packable b32 commits
#pragma unroll
      for (int c = 0; c < 2; ++c) {
        int i = c * 256 + tid;
        int d0 = (i & 15) * 2, kjp = (i >> 4) * 2;
        vpa[c] = *(const ushort2*)(vb + (bTk + krow0 + kjp) * vrs + d0);
        vpb[c] = *(const ushort2*)(vb + (bTk + krow0 + kjp + 1) * vrs + d0);
      }
    };
    auto commit = [&]() {
#pragma unroll
      for (int c = 0; c < 6; ++c) {
        int i = c * 256 + tid;
        int kj = i / 24, dp = (i - kj * 24) * 4;
        *(ushort4*)(Ks + kj * 104 + dp) = kpre[c];
      }
#pragma unroll
      for (int c = 0; c < 2; ++c) {
        int i = c * 256 + tid;
        int d0 = (i & 15) * 2, kjp = (i >> 4) * 2;
        *(unsigned*)(Vts + (d0 + 0) * 72 + kjp) =
            (unsigned)vpa[c].x | ((unsigned)vpb[c].x << 16);
        *(unsigned*)(Vts + (d0 + 1) * 72 + kjp) =
            (unsigned)vpa[c].y | ((unsigned)vpb[c].y << 16);
      }
    };

    f32x4 of[2], lf;
    of[0] = (f32x4){0.f, 0.f, 0.f, 0.f};
    of[1] = (f32x4){0.f, 0.f, 0.f, 0.f};
    lf = (f32x4){0.f, 0.f, 0.f, 0.f};

    int nkt = causal ? (qtile + 1) : (Tk >> 6);
    prefetch(0);
    for (int kt = 0; kt < nkt; ++kt) {
      __syncthreads();  // prior LDS reads complete
      commit();
      __syncthreads();
      if (kt + 1 < nkt) prefetch(kt + 1);
      int krow0 = kt * 64;

      // ---- S = Q K^T ----
      f32x4 sf[4];
#pragma unroll
      for (int nb = 0; nb < 4; ++nb) sf[nb] = (f32x4){0.f, 0.f, 0.f, 0.f};
#pragma unroll
      for (int ks = 0; ks < 3; ++ks) {
        bf16x8 aq = *(const bf16x8*)(Qs + (wv * 16 + l15) * 104 + ks * 32 + quad * 8);
#pragma unroll
        for (int nb = 0; nb < 4; ++nb) {
          bf16x8 bk = *(const bf16x8*)(Ks + (nb * 16 + l15) * 104 + ks * 32 + quad * 8);
          sf[nb] = __builtin_amdgcn_mfma_f32_16x16x32_bf16(aq, bk, sf[nb], 0, 0, 0);
        }
      }
      // C-layout: sf[nb][reg] = S[quad*4+reg][nb*16+l15]
      if (causal && kt == qtile) {
        int rowg = qrow0 + wv * 16 + quad * 4;
#pragma unroll
        for (int reg = 0; reg < 4; ++reg) {
#pragma unroll
          for (int nb = 0; nb < 4; ++nb) {
            int colg = krow0 + nb * 16 + l15;
            if (colg > rowg + reg) sf[nb][reg] = -INFINITY;
          }
        }
      }
      // ---- no-max softmax: p = exp(min(s,30)) ----
      short* Pw = Ps + wv * 16 * 72;
#pragma unroll
      for (int nb = 0; nb < 4; ++nb) {
#pragma unroll
        for (int reg = 0; reg < 4; ++reg) {
          float p = __expf(fminf(sf[nb][reg], 30.f));
          Pw[(quad * 4 + reg) * 72 + nb * 16 + l15] = f2bf(p);
        }
      }
      // wave-private P: in-wave LDS ordering only
      asm volatile("s_waitcnt lgkmcnt(0)" ::: "memory");

      // ---- O += P V, l += P * ones ----
#pragma unroll
      for (int ks2 = 0; ks2 < 2; ++ks2) {
        bf16x8 ap = *(const bf16x8*)(Pw + l15 * 72 + ks2 * 32 + quad * 8);
        lf = __builtin_amdgcn_mfma_f32_16x16x32_bf16(ap, onesf, lf, 0, 0, 0);
#pragma unroll
        for (int vn = 0; vn < 2; ++vn) {
          bf16x8 bv = *(const bf16x8*)(Vts + (vn * 16 + l15) * 72 + ks2 * 32 + quad * 8);
          of[vn] = __builtin_amdgcn_mfma_f32_16x16x32_bf16(ap, bv, of[vn], 0, 0, 0);
        }
      }
    }

    float wgt = bw[b * 3 + s];
#pragma unroll
    for (int reg = 0; reg < 4; ++reg) {
      float inv = wgt / lf[reg];
      oacc[0][reg] += of[0][reg] * inv;
      oacc[1][reg] += of[1][reg] * inv;
    }
  }

  // ---- epilogue: bf16, [b*TT+t][h*32+d] ----
#pragma unroll
  for (int reg = 0; reg < 4; ++reg) {
    int trow = qrow0 + wv * 16 + quad * 4 + reg;
#pragma unroll
    for (int vn = 0; vn < 2; ++vn) {
      attout[(size_t)(b * TT + trow) * 512 + h * 32 + vn * 16 + l15] =
          (ushort)f2bf(oacc[vn][reg]);
    }
  }
}

// ---------------- launch ----------------
extern "C" void kernel_launch(void* const* d_in, const int* in_sizes, int n_in,
                              void* d_out, int out_size, void* d_ws, size_t ws_size,
                              hipStream_t stream) {
  const float* x      = (const float*)d_in[0];
  const float* W_cq   = (const float*)d_in[1];
  const float* qnw    = (const float*)d_in[2];
  const float* W_dqn  = (const float*)d_in[3];
  const float* W_dqr  = (const float*)d_in[4];
  const float* W_ckv  = (const float*)d_in[5];
  const float* kvnw   = (const float*)d_in[6];
  const float* W_dkn  = (const float*)d_in[7];
  const float* W_dv   = (const float*)d_in[8];
  const float* W_kr   = (const float*)d_in[9];
  const float* W_imp  = (const float*)d_in[10];
  const float* b_imp  = (const float*)d_in[11];
  const float* W_selk = (const float*)d_in[12];
  const float* W_selv = (const float*)d_in[13];
  const float* W_wink = (const float*)d_in[14];
  const float* W_winv = (const float*)d_in[15];
  const float* W_gate = (const float*)d_in[16];
  const float* b_gate = (const float*)d_in[17];
  const float* W_proj = (const float*)d_in[18];
  const float* cos_f  = (const float*)d_in[19];
  const float* sin_f  = (const float*)d_in[20];
  float* out = (float*)d_out;
  float* ws  = (float*)d_ws;

  size_t off = 0;
  auto alloc = [&](size_t n) {
    float* p = ws + off;
    off += (n + 255) & ~(size_t)255;
    return p;
  };
  const int ROWS = 2 * TT;  // 4096
  float* xh       = alloc((size_t)ROWS * 256);
  ushort* xbf     = (ushort*)alloc((size_t)ROWS * 128);
  ushort* nqb     = (ushort*)alloc((size_t)ROWS * 48);
  ushort* qbf     = (ushort*)alloc((size_t)ROWS * 768);   // bf16 [qn 512 | qr 1024]
  ushort* nkvb    = (ushort*)alloc((size_t)ROWS * 16);
  ushort* kvtmp   = (ushort*)alloc((size_t)ROWS * 512);   // bf16 [kn 512 | v 512]
  float* krtmp    = alloc((size_t)ROWS * 64);
  ushort* krbf    = (ushort*)alloc((size_t)ROWS * 32);
  float* scores   = alloc(ROWS);
  float* gpart    = alloc((size_t)ROWS * 3);
  float* bwp      = alloc(8);
  int* selidx     = (int*)alloc(1024);
  ushort* seltmp  = (ushort*)alloc((size_t)1024 * 1024);  // bf16 [sk|sv]
  ushort* wintmp  = (ushort*)alloc((size_t)ROWS * 1024);  // bf16 [wk|wv]
  ushort* attoutb = (ushort*)alloc((size_t)ROWS * 256);   // bf16 [4096][512]
  ushort* Wt_q    = (ushort*)alloc((size_t)1536 * 48);
  ushort* Wt_kv   = (ushort*)alloc((size_t)1024 * 16);
  ushort* Wt_sel  = (ushort*)alloc((size_t)2048 * 128);
  ushort* Wt_win  = (ushort*)alloc((size_t)2048 * 128);
  ushort* Wt_proj = (ushort*)alloc((size_t)256 * 256);

  wtconv_all_kernel<<<5312, 256, 0, stream>>>(W_dqn, W_dqr, W_dkn, W_dv, W_selk, W_selv,
                                              W_wink, W_winv, W_proj,
                                              Wt_q, Wt_kv, Wt_sel, Wt_win, Wt_proj);

  logmap_kernel<<<ROWS, 256, 0, stream>>>(x, xh, xbf);
  nq_kernel<<<ROWS, 128, 0, stream>>>(xh, W_cq, qnw, nqb);
  nkv_kernel<<<ROWS, 128, 0, stream>>>(x, W_ckv, kvnw, W_imp, b_imp, W_gate, W_kr,
                                       nkvb, scores, gpart, krtmp);
  gemm_kernel<<<dim3(32, 12), 256, 0, stream>>>(nqb, Wt_q, qbf, nullptr, 96, 1536, 1);
  gemm_kernel<<<dim3(32, 8), 256, 0, stream>>>(nkvb, Wt_kv, kvtmp, nullptr, 32, 1024, 1);
  rope_kernel<<<ROWS, 256, 0, stream>>>(cos_f, sin_f, qbf, krtmp, krbf);
  gate_kernel<<<1, 256, 0, stream>>>(gpart, b_gate, bwp);
  topk_kernel<<<2, 1024, 0, stream>>>(scores, selidx);
  gemm_kernel<<<dim3(8, 16), 256, 0, stream>>>(xbf, Wt_sel, seltmp, selidx, 256, 2048, 1);
  gemm_kernel<<<dim3(32, 16), 256, 0, stream>>>(xbf, Wt_win, wintmp, nullptr, 256, 2048, 1);

  flash_fused_kernel<<<1024, 256, 0, stream>>>(qbf, kvtmp, krbf, seltmp, wintmp, bwp, attoutb);

  gemm_kernel<<<dim3(32, 2), 256, 0, stream>>>(attoutb, Wt_proj, out, nullptr, 512, 256, 0);
}

// Round 7
// 358.660 us; speedup vs baseline: 1.3805x; 1.3805x over previous
//
#include <hip/hip_runtime.h>
#include <hip/hip_bf16.h>
#include <math.h>

#define TT 2048
#define NE 256
#define NHEAD 16

typedef __attribute__((ext_vector_type(8))) short bf16x8;
typedef __attribute__((ext_vector_type(4))) float f32x4;
typedef unsigned short ushort;
typedef __attribute__((ext_vector_type(8))) unsigned short us8;

__device__ __forceinline__ short f2bf(float x) {
  __hip_bfloat16 h = __float2bfloat16(x);
  return *reinterpret_cast<short*>(&h);
}
__device__ __forceinline__ float bf2f(ushort u) {
  unsigned v = ((unsigned)u) << 16;
  return __uint_as_float(v);
}
__device__ __forceinline__ unsigned pack2bf(float a, float b) {
  return (unsigned)(ushort)f2bf(a) | ((unsigned)(ushort)f2bf(b) << 16);
}

// ---------------- 1. logmap (+ x -> bf16 copy) ----------------
__global__ __launch_bounds__(256) void logmap_kernel(const float* __restrict__ x,
                                                     float* __restrict__ xh,
                                                     ushort* __restrict__ xbf) {
  __shared__ float red[16];
  int row = blockIdx.x, tid = threadIdx.x;
  int t = row & (TT - 1);
  float uv = x[row * NE + tid];
  float rv = (t == 0) ? 0.f : x[row * NE - NE + tid];
  xbf[row * NE + tid] = (ushort)f2bf(uv);
  float a = rv * rv, bq = uv * uv, c2 = -rv * uv;
#pragma unroll
  for (int off = 32; off > 0; off >>= 1) {
    a += __shfl_down(a, off, 64);
    bq += __shfl_down(bq, off, 64);
    c2 += __shfl_down(c2, off, 64);
  }
  if ((tid & 63) == 0) {
    int w = tid >> 6;
    red[w] = a; red[4 + w] = bq; red[8 + w] = c2;
  }
  __syncthreads();
  float xn2 = red[0] + red[1] + red[2] + red[3];
  float un2 = red[4] + red[5] + red[6] + red[7];
  float ip  = red[8] + red[9] + red[10] + red[11];
  float den = 1.f + 2.f * ip + xn2 * un2;
  float mob = ((1.f + 2.f * ip + un2) * (-rv) + (1.f - xn2) * uv) / den;
  float m2 = mob * mob;
#pragma unroll
  for (int off = 32; off > 0; off >>= 1) m2 += __shfl_down(m2, off, 64);
  if ((tid & 63) == 0) red[12 + (tid >> 6)] = m2;
  __syncthreads();
  float an2 = red[12] + red[13] + red[14] + red[15];
  float an = sqrtf(an2);
  float cf = 1.f + xn2;
  float arg = fminf(sqrtf(an), 0.999f);
  xh[row * NE + tid] = cf * atanhf(arg) * mob / an;
}

// ---------------- 2. nq = rmsnorm(xh @ W_cq) -> bf16 ----------------
__global__ __launch_bounds__(128) void nq_kernel(const float* __restrict__ xh,
                                                 const float* __restrict__ W_cq,
                                                 const float* __restrict__ qnw,
                                                 ushort* __restrict__ nqb) {
  int row = blockIdx.x, tid = threadIdx.x;  // 128 thr
  __shared__ float xr[256];
  __shared__ float red[128];
  xr[tid] = xh[row * 256 + tid];
  xr[tid + 128] = xh[row * 256 + tid + 128];
  __syncthreads();
  float acc = 0.f;
  if (tid < 96) {
    const float* wp = W_cq + tid;
#pragma unroll 4
    for (int k = 0; k < 256; ++k) acc += xr[k] * wp[k * 96];
  }
  red[tid] = (tid < 96) ? acc * acc : 0.f;
  __syncthreads();
  for (int s = 64; s > 0; s >>= 1) {
    if (tid < s) red[tid] += red[tid + s];
    __syncthreads();
  }
  float sc = rsqrtf(red[0] / 96.f + 1e-6f);
  if (tid < 96) nqb[row * 96 + tid] = (ushort)f2bf(acc * sc * qnw[tid]);
}

// ---------------- 3. nkv(bf16) + imp scores + gate partials + kr ----------------
__global__ __launch_bounds__(128) void nkv_kernel(const float* __restrict__ x,
                                                  const float* __restrict__ W_ckv,
                                                  const float* __restrict__ kvnw,
                                                  const float* __restrict__ W_imp,
                                                  const float* __restrict__ b_imp,
                                                  const float* __restrict__ W_gate,
                                                  const float* __restrict__ W_kr,
                                                  ushort* __restrict__ nkvb,
                                                  float* __restrict__ scores,
                                                  float* __restrict__ gpart,
                                                  float* __restrict__ krtmp) {
  int row = blockIdx.x, tid = threadIdx.x;  // 128 thr
  __shared__ float xr[256];
  xr[tid] = x[row * 256 + tid];
  xr[tid + 128] = x[row * 256 + tid + 128];
  __syncthreads();
  const float* wp;
  int stride;
  if (tid < 32) { wp = W_ckv + tid; stride = 32; }
  else if (tid == 32) { wp = W_imp; stride = 1; }
  else if (tid < 36) { wp = W_gate + (tid - 33); stride = 3; }
  else if (tid < 100) { wp = W_kr + (tid - 36); stride = 64; }
  else { wp = W_ckv; stride = 0; }
  float acc = 0.f;
#pragma unroll 4
  for (int k = 0; k < 256; ++k) acc += xr[k] * wp[k * stride];
  float ss = acc * acc;
#pragma unroll
  for (int off = 16; off > 0; off >>= 1) ss += __shfl_xor(ss, off, 64);
  if (tid < 32) {
    float sc = rsqrtf(ss / 32.f + 1e-6f);
    nkvb[row * 32 + tid] = (ushort)f2bf(acc * sc * kvnw[tid]);
  } else if (tid == 32) {
    scores[row] = acc + b_imp[0];
  } else if (tid < 36) {
    gpart[row * 3 + (tid - 33)] = acc;
  } else if (tid < 100) {
    krtmp[row * 64 + (tid - 36)] = acc;
  }
}

// ---------------- merged weight convert ----------------
__global__ __launch_bounds__(256) void wtconv_all_kernel(
    const float* __restrict__ W_dqn, const float* __restrict__ W_dqr,
    const float* __restrict__ W_dkn, const float* __restrict__ W_dv,
    const float* __restrict__ W_selk, const float* __restrict__ W_selv,
    const float* __restrict__ W_wink, const float* __restrict__ W_winv,
    const float* __restrict__ W_proj,
    ushort* __restrict__ Wt_q, ushort* __restrict__ Wt_kv,
    ushort* __restrict__ Wt_sel, ushort* __restrict__ Wt_win,
    ushort* __restrict__ Wt_proj) {
  int i = blockIdx.x * 256 + threadIdx.x;
  const float scale = 0.1020620726159658f;
  if (i < 147456) {  // Wt_q [1536][96]
    int n = i / 96, k = i - n * 96;
    float v = (n < 512) ? W_dqn[(size_t)k * 512 + n] : W_dqr[(size_t)k * 1024 + (n - 512)];
    Wt_q[i] = (ushort)f2bf(v * scale);
  } else if (i < 180224) {  // Wt_kv [1024][32]
    int j = i - 147456;
    int n = j / 32, k = j & 31;
    float v = (n < 512) ? W_dkn[(size_t)k * 512 + n] : W_dv[(size_t)k * 512 + (n - 512)];
    Wt_kv[j] = (ushort)f2bf(v);
  } else if (i < 704512) {  // Wt_sel [2048][256]
    int j = i - 180224;
    int n = j >> 8, k = j & 255;
    float v = (n < 1536) ? W_selk[(size_t)k * 1536 + n] : W_selv[(size_t)k * 512 + (n - 1536)];
    Wt_sel[j] = (ushort)f2bf(v);
  } else if (i < 1228800) {  // Wt_win [2048][256]
    int j = i - 704512;
    int n = j >> 8, k = j & 255;
    float v = (n < 1536) ? W_wink[(size_t)k * 1536 + n] : W_winv[(size_t)k * 512 + (n - 1536)];
    Wt_win[j] = (ushort)f2bf(v);
  } else if (i < 1359872) {  // Wt_proj [256][512]
    int j = i - 1228800;
    int n = j >> 9, k = j & 511;
    Wt_proj[j] = (ushort)f2bf(W_proj[(size_t)k * 256 + n]);
  }
}

// ---------------- bf16 MFMA GEMM ----------------
__global__ __launch_bounds__(256) void gemm_kernel(const ushort* __restrict__ A,
                                                   const ushort* __restrict__ Bt,
                                                   void* __restrict__ Out,
                                                   const int* __restrict__ selidx,
                                                   int K, int ldo, int obf16) {
  __shared__ __align__(16) short As[128 * 40];
  __shared__ __align__(16) short Bs[128 * 40];
  int m0 = blockIdx.x * 128, n0 = blockIdx.y * 128;
  int tid = threadIdx.x;
  int wv = tid >> 6, lane = tid & 63;
  int l15 = lane & 15, quad = lane >> 4;
  int wm = wv >> 1, wn = wv & 1;

  int r = tid >> 1, seg = tid & 1;
  int arow = m0 + r;
  if (selidx) arow = ((arow >> 9) * TT) + selidx[m0 + r];
  const ushort* ga = A + (size_t)arow * K + seg * 16;
  const ushort* gb = Bt + (size_t)(n0 + r) * K + seg * 16;

  f32x4 acc[4][4];
#pragma unroll
  for (int i = 0; i < 4; ++i)
#pragma unroll
    for (int j = 0; j < 4; ++j) acc[i][j] = (f32x4){0.f, 0.f, 0.f, 0.f};

  int nk = K >> 5;
  us8 apre0 = *(const us8*)ga, apre1 = *(const us8*)(ga + 8);
  us8 bpre0 = *(const us8*)gb, bpre1 = *(const us8*)(gb + 8);
  for (int kk = 0; kk < nk; ++kk) {
    __syncthreads();
    *(us8*)(As + r * 40 + seg * 16) = apre0;
    *(us8*)(As + r * 40 + seg * 16 + 8) = apre1;
    *(us8*)(Bs + r * 40 + seg * 16) = bpre0;
    *(us8*)(Bs + r * 40 + seg * 16 + 8) = bpre1;
    __syncthreads();
    if (kk + 1 < nk) {
      apre0 = *(const us8*)(ga + (kk + 1) * 32);
      apre1 = *(const us8*)(ga + (kk + 1) * 32 + 8);
      bpre0 = *(const us8*)(gb + (kk + 1) * 32);
      bpre1 = *(const us8*)(gb + (kk + 1) * 32 + 8);
    }
    bf16x8 af[4], bf[4];
#pragma unroll
    for (int mf = 0; mf < 4; ++mf)
      af[mf] = *(const bf16x8*)(As + (wm * 64 + mf * 16 + l15) * 40 + quad * 8);
#pragma unroll
    for (int nf = 0; nf < 4; ++nf)
      bf[nf] = *(const bf16x8*)(Bs + (wn * 64 + nf * 16 + l15) * 40 + quad * 8);
#pragma unroll
    for (int mf = 0; mf < 4; ++mf)
#pragma unroll
      for (int nf = 0; nf < 4; ++nf)
        acc[mf][nf] = __builtin_amdgcn_mfma_f32_16x16x32_bf16(af[mf], bf[nf], acc[mf][nf], 0, 0, 0);
  }

#pragma unroll
  for (int mf = 0; mf < 4; ++mf) {
#pragma unroll
    for (int nf = 0; nf < 4; ++nf) {
#pragma unroll
      for (int reg = 0; reg < 4; ++reg) {
        int row = m0 + wm * 64 + mf * 16 + quad * 4 + reg;
        int col = n0 + wn * 64 + nf * 16 + l15;
        size_t oi = (size_t)row * ldo + col;
        float v = acc[mf][nf][reg];
        if (obf16) ((ushort*)Out)[oi] = (ushort)f2bf(v);
        else ((float*)Out)[oi] = v;
      }
    }
  }
}

// ---------------- rope: qbf (bf16, in place) + kr -> bf16 ----------------
__global__ __launch_bounds__(256) void rope_kernel(const float* __restrict__ cos_t,
                                                   const float* __restrict__ sin_t,
                                                   ushort* __restrict__ qbf,
                                                   const float* __restrict__ krtmp,
                                                   ushort* __restrict__ krbf) {
  int row = blockIdx.x, tid = threadIdx.x;
  int t = row & (TT - 1);
  for (int i = tid; i < 544; i += 256) {
    int dd = (i < 512) ? (i & 31) : (i - 512);
    float c = cos_t[t * 32 + dd], s = sin_t[t * 32 + dd];
    if (i < 512) {
      int h = i >> 5;
      ushort* p0 = qbf + (size_t)row * 1536 + 512 + h * 64 + dd;
      float xr = bf2f(p0[0]), xi = bf2f(p0[32]);
      p0[0] = (ushort)f2bf(xr * c - xi * s);
      p0[32] = (ushort)f2bf(xr * s + xi * c);
    } else {
      const float* p0 = krtmp + (size_t)row * 64 + dd;
      float xr = p0[0], xi = p0[32];
      krbf[(size_t)row * 64 + dd] = (ushort)f2bf(xr * c - xi * s);
      krbf[(size_t)row * 64 + dd + 32] = (ushort)f2bf(xr * s + xi * c);
    }
  }
}

// ---------------- gate finalize ----------------
__global__ __launch_bounds__(256) void gate_kernel(const float* __restrict__ gpart,
                                                   const float* __restrict__ b_gate,
                                                   float* __restrict__ bw) {
  int tid = threadIdx.x;  // 256
  float a0 = 0, a1 = 0, a2 = 0, a3 = 0, a4 = 0, a5 = 0;
  for (int r = tid; r < 2 * TT; r += 256) {
    float g0 = gpart[r * 3], g1 = gpart[r * 3 + 1], g2 = gpart[r * 3 + 2];
    if (r < TT) { a0 += g0; a1 += g1; a2 += g2; }
    else { a3 += g0; a4 += g1; a5 += g2; }
  }
  __shared__ float red[6][256];
  red[0][tid] = a0; red[1][tid] = a1; red[2][tid] = a2;
  red[3][tid] = a3; red[4][tid] = a4; red[5][tid] = a5;
  __syncthreads();
  for (int s = 128; s > 0; s >>= 1) {
    if (tid < s) {
#pragma unroll
      for (int q = 0; q < 6; ++q) red[q][tid] += red[q][tid + s];
    }
    __syncthreads();
  }
  if (tid == 0) {
    for (int b = 0; b < 2; ++b) {
      float v[3];
      float mx = -INFINITY;
      for (int j = 0; j < 3; ++j) {
        v[j] = red[b * 3 + j][0] / (float)TT + b_gate[j];
        mx = fmaxf(mx, v[j]);
      }
      float sum = 0.f;
      for (int j = 0; j < 3; ++j) { v[j] = expf(v[j] - mx); sum += v[j]; }
      for (int j = 0; j < 3; ++j) bw[b * 3 + j] = v[j] / sum;
    }
  }
}

// ---------------- top-k stage 1: ranks -> flags (64 blocks, parallel) ----------------
// rank_i = #{v_j > v_i} + #{v_j == v_i, j < i}; flag = rank < 512.
__global__ __launch_bounds__(1024) void topk_rank_kernel(const float* __restrict__ scores,
                                                         int* __restrict__ flags) {
  int b = blockIdx.y, blk = blockIdx.x;  // 32 blocks/batch
  int tid = threadIdx.x;
  __shared__ unsigned sk[TT];
#pragma unroll
  for (int e = 0; e < 2; ++e) {
    int i = tid + e * 1024;
    float s = scores[b * TT + i];
    unsigned u = __float_as_uint(s);
    u = (u & 0x80000000u) ? ~u : (u | 0x80000000u);  // order-preserving map
    sk[i] = u;
  }
  __syncthreads();
  // 64 elements/block; 16 threads per element, each scans 128 candidates
  int e = blk * 64 + (tid >> 4);
  int sub = tid & 15;
  unsigned u = sk[e];
  int r = 0;
  int j0 = sub * 128;
#pragma unroll 8
  for (int j = j0; j < j0 + 128; ++j) {
    unsigned v = sk[j];
    r += (int)((v > u) || (v == u && j < e));
  }
#pragma unroll
  for (int off = 8; off > 0; off >>= 1) r += __shfl_down(r, off, 16);
  if (sub == 0) flags[b * TT + e] = (r < 512) ? 1 : 0;
}

// ---------------- top-k stage 2: scan + scatter (1 block/batch) ----------------
__global__ __launch_bounds__(1024) void topk_scan_kernel(const int* __restrict__ flags,
                                                         int* __restrict__ selidx) {
  int b = blockIdx.x, tid = threadIdx.x;
  __shared__ int pre[TT];
  int f0 = flags[b * TT + tid], f1 = flags[b * TT + tid + 1024];
  pre[tid] = f0;
  pre[tid + 1024] = f1;
  __syncthreads();
  for (int off = 1; off < TT; off <<= 1) {
    int a0 = (tid >= off) ? pre[tid - off] : 0;
    int a1 = (tid + 1024 >= off) ? pre[tid + 1024 - off] : 0;
    __syncthreads();
    pre[tid] += a0;
    pre[tid + 1024] += a1;
    __syncthreads();
  }
  if (f0) selidx[b * 512 + pre[tid] - 1] = tid;
  if (f1) selidx[b * 512 + pre[tid + 1024] - 1] = tid + 1024;
}

// ---------------- fused MFMA flash attention (cmp + sel + win) ----------------
__global__ __launch_bounds__(256) void flash_fused_kernel(
    const ushort* __restrict__ qbf,    // [row][qn 512 | qr 1024] bf16, scale folded
    const ushort* __restrict__ kv,     // [row][kn 512 | v 512] bf16
    const ushort* __restrict__ krbf,   // [row][64] bf16 (roped)
    const ushort* __restrict__ selt,   // [selrow][sk 1536 | sv 512] bf16
    const ushort* __restrict__ wint,   // [row][wk 1536 | wv 512] bf16
    const float* __restrict__ bw,
    ushort* __restrict__ attout) {     // [b*TT+t][h*32+d] bf16
  __shared__ __align__(16) short Qs[64 * 104];
  __shared__ __align__(16) short Ks[64 * 104];
  __shared__ __align__(16) short Vts[32 * 72];
  __shared__ __align__(16) short Ps[4 * 16 * 72];

  int bx = blockIdx.x;
  int qtile = 31 - (bx >> 5);  // heavy-first dispatch
  int bh = bx & 31;
  int b = bh >> 4, h = bh & 15;
  int tid = threadIdx.x;
  int wv = tid >> 6, lane = tid & 63;
  int l15 = lane & 15, quad = lane >> 4;
  const bf16x8 onesf = {16256, 16256, 16256, 16256, 16256, 16256, 16256, 16256};

  int qrow0 = qtile * 64;
  for (int i = tid; i < 64 * 24; i += 256) {
    int qi = i / 24, dp = (i - qi * 24) * 4;
    int col = (dp < 32) ? (h * 32 + dp) : (512 + h * 64 + (dp - 32));
    ushort4 q4 = *(const ushort4*)(qbf + (size_t)(b * TT + qrow0 + qi) * 1536 + col);
    *(ushort4*)(Qs + qi * 104 + dp) = q4;
  }

  f32x4 oacc[2];
  oacc[0] = (f32x4){0.f, 0.f, 0.f, 0.f};
  oacc[1] = (f32x4){0.f, 0.f, 0.f, 0.f};

  ushort4 kpre[6];
  ushort2 vpa[2], vpb[2];

  for (int s = 0; s < 3; ++s) {
    const ushort *kb1, *kb2, *vb;
    size_t krs1, krs2, vrs;
    int split, Tk, causal;
    if (s == 0) {  // cmp
      kb1 = kv + h * 32;        krs1 = 1024; split = 32;
      kb2 = krbf;               krs2 = 64;
      vb = kv + 512 + h * 32;   vrs = 1024;
      Tk = TT; causal = 1;
    } else if (s == 1) {  // sel
      kb1 = selt + h * 96;      krs1 = 2048; split = 96;
      kb2 = selt;               krs2 = 2048;
      vb = selt + 1536 + h * 32; vrs = 2048;
      Tk = 512; causal = 0;
    } else {  // win
      kb1 = wint + h * 96;      krs1 = 2048; split = 96;
      kb2 = wint;               krs2 = 2048;
      vb = wint + 1536 + h * 32; vrs = 2048;
      Tk = TT; causal = 1;
    }
    size_t bTk = (size_t)b * Tk;

    auto prefetch = [&](int kt) {
      int krow0 = kt * 64;
#pragma unroll
      for (int c = 0; c < 6; ++c) {
        int i = c * 256 + tid;
        int kj = i / 24, dp = (i - kj * 24) * 4;
        const ushort* src = (dp < split)
                                ? kb1 + (bTk + krow0 + kj) * krs1 + dp
                                : kb2 + (bTk + krow0 + kj) * krs2 + (dp - split);
        kpre[c] = *(const ushort4*)src;
      }
#pragma unroll
      for (int c = 0; c < 2; ++c) {
        int i = c * 256 + tid;
        int d0 = (i & 15) * 2, kjp = (i >> 4) * 2;
        vpa[c] = *(const ushort2*)(vb + (bTk + krow0 + kjp) * vrs + d0);
        vpb[c] = *(const ushort2*)(vb + (bTk + krow0 + kjp + 1) * vrs + d0);
      }
    };
    auto commit = [&]() {
#pragma unroll
      for (int c = 0; c < 6; ++c) {
        int i = c * 256 + tid;
        int kj = i / 24, dp = (i - kj * 24) * 4;
        *(ushort4*)(Ks + kj * 104 + dp) = kpre[c];
      }
#pragma unroll
      for (int c = 0; c < 2; ++c) {
        int i = c * 256 + tid;
        int d0 = (i & 15) * 2, kjp = (i >> 4) * 2;
        *(unsigned*)(Vts + (d0 + 0) * 72 + kjp) =
            (unsigned)vpa[c].x | ((unsigned)vpb[c].x << 16);
        *(unsigned*)(Vts + (d0 + 1) * 72 + kjp) =
            (unsigned)vpa[c].y | ((unsigned)vpb[c].y << 16);
      }
    };

    f32x4 of[2], lf;
    of[0] = (f32x4){0.f, 0.f, 0.f, 0.f};
    of[1] = (f32x4){0.f, 0.f, 0.f, 0.f};
    lf = (f32x4){0.f, 0.f, 0.f, 0.f};

    int nkt = causal ? (qtile + 1) : (Tk >> 6);
    prefetch(0);
    for (int kt = 0; kt < nkt; ++kt) {
      __syncthreads();
      commit();
      __syncthreads();
      if (kt + 1 < nkt) prefetch(kt + 1);
      int krow0 = kt * 64;

      f32x4 sf[4];
#pragma unroll
      for (int nb = 0; nb < 4; ++nb) sf[nb] = (f32x4){0.f, 0.f, 0.f, 0.f};
#pragma unroll
      for (int ks = 0; ks < 3; ++ks) {
        bf16x8 aq = *(const bf16x8*)(Qs + (wv * 16 + l15) * 104 + ks * 32 + quad * 8);
#pragma unroll
        for (int nb = 0; nb < 4; ++nb) {
          bf16x8 bk = *(const bf16x8*)(Ks + (nb * 16 + l15) * 104 + ks * 32 + quad * 8);
          sf[nb] = __builtin_amdgcn_mfma_f32_16x16x32_bf16(aq, bk, sf[nb], 0, 0, 0);
        }
      }
      if (causal && kt == qtile) {
        int rowg = qrow0 + wv * 16 + quad * 4;
#pragma unroll
        for (int reg = 0; reg < 4; ++reg) {
#pragma unroll
          for (int nb = 0; nb < 4; ++nb) {
            int colg = krow0 + nb * 16 + l15;
            if (colg > rowg + reg) sf[nb][reg] = -INFINITY;
          }
        }
      }
      short* Pw = Ps + wv * 16 * 72;
#pragma unroll
      for (int nb = 0; nb < 4; ++nb) {
#pragma unroll
        for (int reg = 0; reg < 4; ++reg) {
          float p = __expf(fminf(sf[nb][reg], 30.f));
          Pw[(quad * 4 + reg) * 72 + nb * 16 + l15] = f2bf(p);
        }
      }
      asm volatile("s_waitcnt lgkmcnt(0)" ::: "memory");

#pragma unroll
      for (int ks2 = 0; ks2 < 2; ++ks2) {
        bf16x8 ap = *(const bf16x8*)(Pw + l15 * 72 + ks2 * 32 + quad * 8);
        lf = __builtin_amdgcn_mfma_f32_16x16x32_bf16(ap, onesf, lf, 0, 0, 0);
#pragma unroll
        for (int vn = 0; vn < 2; ++vn) {
          bf16x8 bv = *(const bf16x8*)(Vts + (vn * 16 + l15) * 72 + ks2 * 32 + quad * 8);
          of[vn] = __builtin_amdgcn_mfma_f32_16x16x32_bf16(ap, bv, of[vn], 0, 0, 0);
        }
      }
    }

    float wgt = bw[b * 3 + s];
#pragma unroll
    for (int reg = 0; reg < 4; ++reg) {
      float inv = wgt / lf[reg];
      oacc[0][reg] += of[0][reg] * inv;
      oacc[1][reg] += of[1][reg] * inv;
    }
  }

#pragma unroll
  for (int reg = 0; reg < 4; ++reg) {
    int trow = qrow0 + wv * 16 + quad * 4 + reg;
#pragma unroll
    for (int vn = 0; vn < 2; ++vn) {
      attout[(size_t)(b * TT + trow) * 512 + h * 32 + vn * 16 + l15] =
          (ushort)f2bf(oacc[vn][reg]);
    }
  }
}

// ---------------- launch ----------------
extern "C" void kernel_launch(void* const* d_in, const int* in_sizes, int n_in,
                              void* d_out, int out_size, void* d_ws, size_t ws_size,
                              hipStream_t stream) {
  const float* x      = (const float*)d_in[0];
  const float* W_cq   = (const float*)d_in[1];
  const float* qnw    = (const float*)d_in[2];
  const float* W_dqn  = (const float*)d_in[3];
  const float* W_dqr  = (const float*)d_in[4];
  const float* W_ckv  = (const float*)d_in[5];
  const float* kvnw   = (const float*)d_in[6];
  const float* W_dkn  = (const float*)d_in[7];
  const float* W_dv   = (const float*)d_in[8];
  const float* W_kr   = (const float*)d_in[9];
  const float* W_imp  = (const float*)d_in[10];
  const float* b_imp  = (const float*)d_in[11];
  const float* W_selk = (const float*)d_in[12];
  const float* W_selv = (const float*)d_in[13];
  const float* W_wink = (const float*)d_in[14];
  const float* W_winv = (const float*)d_in[15];
  const float* W_gate = (const float*)d_in[16];
  const float* b_gate = (const float*)d_in[17];
  const float* W_proj = (const float*)d_in[18];
  const float* cos_f  = (const float*)d_in[19];
  const float* sin_f  = (const float*)d_in[20];
  float* out = (float*)d_out;
  float* ws  = (float*)d_ws;

  size_t off = 0;
  auto alloc = [&](size_t n) {
    float* p = ws + off;
    off += (n + 255) & ~(size_t)255;
    return p;
  };
  const int ROWS = 2 * TT;  // 4096
  float* xh       = alloc((size_t)ROWS * 256);
  ushort* xbf     = (ushort*)alloc((size_t)ROWS * 128);
  ushort* nqb     = (ushort*)alloc((size_t)ROWS * 48);
  ushort* qbf     = (ushort*)alloc((size_t)ROWS * 768);   // bf16 [qn 512 | qr 1024]
  ushort* nkvb    = (ushort*)alloc((size_t)ROWS * 16);
  ushort* kvtmp   = (ushort*)alloc((size_t)ROWS * 512);   // bf16 [kn 512 | v 512]
  float* krtmp    = alloc((size_t)ROWS * 64);
  ushort* krbf    = (ushort*)alloc((size_t)ROWS * 32);
  float* scores   = alloc(ROWS);
  float* gpart    = alloc((size_t)ROWS * 3);
  float* bwp      = alloc(8);
  int* selidx     = (int*)alloc(1024);
  int* selflags   = (int*)alloc(ROWS);
  ushort* seltmp  = (ushort*)alloc((size_t)1024 * 1024);  // bf16 [sk|sv]
  ushort* wintmp  = (ushort*)alloc((size_t)ROWS * 1024);  // bf16 [wk|wv]
  ushort* attoutb = (ushort*)alloc((size_t)ROWS * 256);   // bf16 [4096][512]
  ushort* Wt_q    = (ushort*)alloc((size_t)1536 * 48);
  ushort* Wt_kv   = (ushort*)alloc((size_t)1024 * 16);
  ushort* Wt_sel  = (ushort*)alloc((size_t)2048 * 128);
  ushort* Wt_win  = (ushort*)alloc((size_t)2048 * 128);
  ushort* Wt_proj = (ushort*)alloc((size_t)256 * 256);

  wtconv_all_kernel<<<5312, 256, 0, stream>>>(W_dqn, W_dqr, W_dkn, W_dv, W_selk, W_selv,
                                              W_wink, W_winv, W_proj,
                                              Wt_q, Wt_kv, Wt_sel, Wt_win, Wt_proj);

  logmap_kernel<<<ROWS, 256, 0, stream>>>(x, xh, xbf);
  nq_kernel<<<ROWS, 128, 0, stream>>>(xh, W_cq, qnw, nqb);
  nkv_kernel<<<ROWS, 128, 0, stream>>>(x, W_ckv, kvnw, W_imp, b_imp, W_gate, W_kr,
                                       nkvb, scores, gpart, krtmp);
  gemm_kernel<<<dim3(32, 12), 256, 0, stream>>>(nqb, Wt_q, qbf, nullptr, 96, 1536, 1);
  gemm_kernel<<<dim3(32, 8), 256, 0, stream>>>(nkvb, Wt_kv, kvtmp, nullptr, 32, 1024, 1);
  rope_kernel<<<ROWS, 256, 0, stream>>>(cos_f, sin_f, qbf, krtmp, krbf);
  gate_kernel<<<1, 256, 0, stream>>>(gpart, b_gate, bwp);
  topk_rank_kernel<<<dim3(32, 2), 1024, 0, stream>>>(scores, selflags);
  topk_scan_kernel<<<2, 1024, 0, stream>>>(selflags, selidx);
  gemm_kernel<<<dim3(8, 16), 256, 0, stream>>>(xbf, Wt_sel, seltmp, selidx, 256, 2048, 1);
  gemm_kernel<<<dim3(32, 16), 256, 0, stream>>>(xbf, Wt_win, wintmp, nullptr, 256, 2048, 1);

  flash_fused_kernel<<<1024, 256, 0, stream>>>(qbf, kvtmp, krbf, seltmp, wintmp, bwp, attoutb);

  gemm_kernel<<<dim3(32, 2), 256, 0, stream>>>(attoutb, Wt_proj, out, nullptr, 512, 256, 0);
}

// Round 8
// 318.306 us; speedup vs baseline: 1.5555x; 1.1268x over previous
//
#include <hip/hip_runtime.h>
#include <hip/hip_bf16.h>
#include <math.h>

#define TT 2048
#define NE 256
#define NHEAD 16

typedef __attribute__((ext_vector_type(8))) short bf16x8;
typedef __attribute__((ext_vector_type(4))) float f32x4;
typedef __attribute__((ext_vector_type(16))) float f32x16;
typedef unsigned short ushort;
typedef __attribute__((ext_vector_type(8))) unsigned short us8;

__device__ __forceinline__ short f2bf(float x) {
  __hip_bfloat16 h = __float2bfloat16(x);
  return *reinterpret_cast<short*>(&h);
}
__device__ __forceinline__ float bf2f(ushort u) {
  unsigned v = ((unsigned)u) << 16;
  return __uint_as_float(v);
}

// ---------------- 1. logmap -> xh bf16 (+ x -> bf16 copy) ----------------
__global__ __launch_bounds__(256) void logmap_kernel(const float* __restrict__ x,
                                                     ushort* __restrict__ xhb,
                                                     ushort* __restrict__ xbf) {
  __shared__ float red[16];
  int row = blockIdx.x, tid = threadIdx.x;
  int t = row & (TT - 1);
  float uv = x[row * NE + tid];
  float rv = (t == 0) ? 0.f : x[row * NE - NE + tid];
  xbf[row * NE + tid] = (ushort)f2bf(uv);
  float a = rv * rv, bq = uv * uv, c2 = -rv * uv;
#pragma unroll
  for (int off = 32; off > 0; off >>= 1) {
    a += __shfl_down(a, off, 64);
    bq += __shfl_down(bq, off, 64);
    c2 += __shfl_down(c2, off, 64);
  }
  if ((tid & 63) == 0) {
    int w = tid >> 6;
    red[w] = a; red[4 + w] = bq; red[8 + w] = c2;
  }
  __syncthreads();
  float xn2 = red[0] + red[1] + red[2] + red[3];
  float un2 = red[4] + red[5] + red[6] + red[7];
  float ip  = red[8] + red[9] + red[10] + red[11];
  float den = 1.f + 2.f * ip + xn2 * un2;
  float mob = ((1.f + 2.f * ip + un2) * (-rv) + (1.f - xn2) * uv) / den;
  float m2 = mob * mob;
#pragma unroll
  for (int off = 32; off > 0; off >>= 1) m2 += __shfl_down(m2, off, 64);
  if ((tid & 63) == 0) red[12 + (tid >> 6)] = m2;
  __syncthreads();
  float an2 = red[12] + red[13] + red[14] + red[15];
  float an = sqrtf(an2);
  float cf = 1.f + xn2;
  float arg = fminf(sqrtf(an), 0.999f);
  xhb[row * NE + tid] = (ushort)f2bf(cf * atanhf(arg) * mob / an);
}

// ---------------- merged weight convert (7 outputs, coalesced reads) ----------------
__global__ __launch_bounds__(256) void wtconv_all_kernel(
    const float* __restrict__ W_dqn, const float* __restrict__ W_dqr,
    const float* __restrict__ W_dkn, const float* __restrict__ W_dv,
    const float* __restrict__ W_selk, const float* __restrict__ W_selv,
    const float* __restrict__ W_wink, const float* __restrict__ W_winv,
    const float* __restrict__ W_proj, const float* __restrict__ W_cq,
    const float* __restrict__ W_ckv, const float* __restrict__ W_kr,
    const float* __restrict__ W_gate, const float* __restrict__ W_imp,
    ushort* __restrict__ Wt_q, ushort* __restrict__ Wt_kv,
    ushort* __restrict__ Wt_sel, ushort* __restrict__ Wt_win,
    ushort* __restrict__ Wt_proj, ushort* __restrict__ Wt_cq,
    ushort* __restrict__ Wt_nkv) {
  int i = blockIdx.x * 256 + threadIdx.x;
  const float scale = 0.1020620726159658f;  // 1/sqrt(96) folded into Wt_q
  if (i < 147456) {  // Wt_q [1536 n][96 k]
    int k = i / 1536, n = i - k * 1536;
    float v = (n < 512) ? W_dqn[(size_t)k * 512 + n] : W_dqr[(size_t)k * 1024 + (n - 512)];
    Wt_q[(size_t)n * 96 + k] = (ushort)f2bf(v * scale);
  } else if (i < 180224) {  // Wt_kv [1024 n][32 k]
    int j = i - 147456;
    int k = j >> 10, n = j & 1023;
    float v = (n < 512) ? W_dkn[(size_t)k * 512 + n] : W_dv[(size_t)k * 512 + (n - 512)];
    Wt_kv[(size_t)n * 32 + k] = (ushort)f2bf(v);
  } else if (i < 704512) {  // Wt_sel [2048 n][256 k]
    int j = i - 180224;
    int k = j >> 11, n = j & 2047;
    float v = (n < 1536) ? W_selk[(size_t)k * 1536 + n] : W_selv[(size_t)k * 512 + (n - 1536)];
    Wt_sel[(size_t)n * 256 + k] = (ushort)f2bf(v);
  } else if (i < 1228800) {  // Wt_win [2048 n][256 k]
    int j = i - 704512;
    int k = j >> 11, n = j & 2047;
    float v = (n < 1536) ? W_wink[(size_t)k * 1536 + n] : W_winv[(size_t)k * 512 + (n - 1536)];
    Wt_win[(size_t)n * 256 + k] = (ushort)f2bf(v);
  } else if (i < 1359872) {  // Wt_proj [256 n][512 k]
    int j = i - 1228800;
    int k = j >> 8, n = j & 255;
    Wt_proj[(size_t)n * 512 + k] = (ushort)f2bf(W_proj[(size_t)k * 256 + n]);
  } else if (i < 1392640) {  // Wt_cq [128 n][256 k] (pad n>=96 zero)
    int j = i - 1359872;
    int k = j >> 7, n = j & 127;
    float v = (n < 96) ? W_cq[(size_t)k * 96 + n] : 0.f;
    Wt_cq[(size_t)n * 256 + k] = (ushort)f2bf(v);
  } else if (i < 1425408) {  // Wt_nkv [128 n][256 k]: [ckv32|kr64|gate3|imp1|pad]
    int j = i - 1392640;
    int k = j >> 7, n = j & 127;
    float v;
    if (n < 32) v = W_ckv[(size_t)k * 32 + n];
    else if (n < 96) v = W_kr[(size_t)k * 64 + (n - 32)];
    else if (n < 99) v = W_gate[(size_t)k * 3 + (n - 96)];
    else if (n == 99) v = W_imp[k];
    else v = 0.f;
    Wt_nkv[(size_t)n * 256 + k] = (ushort)f2bf(v);
  }
}

// ---------------- bf16 MFMA GEMM: D[m][n] = sum_k A[m][k] * Bt[n][k] ----------------
// z-dispatch: blockIdx.z==1 uses (A2,Bt2,Out2). ropemode: q-rope fused in epilogue.
__global__ __launch_bounds__(256) void gemm_kernel(const ushort* __restrict__ A,
                                                   const ushort* __restrict__ Bt,
                                                   void* __restrict__ Out,
                                                   const ushort* __restrict__ A2,
                                                   const ushort* __restrict__ Bt2,
                                                   void* __restrict__ Out2,
                                                   const int* __restrict__ selidx,
                                                   const float* __restrict__ cosp,
                                                   const float* __restrict__ sinp,
                                                   int K, int ldo, int obf16, int ropemode) {
  __shared__ __align__(16) short As[128 * 40];
  __shared__ __align__(16) short Bs[128 * 40];
  if (blockIdx.z == 1) { A = A2; Bt = Bt2; Out = Out2; }
  int m0 = blockIdx.x * 128, n0 = blockIdx.y * 128;
  int tid = threadIdx.x;
  int wv = tid >> 6, lane = tid & 63;
  int l15 = lane & 15, quad = lane >> 4;
  int wm = wv >> 1, wn = wv & 1;

  int r = tid >> 1, seg = tid & 1;
  int arow = m0 + r;
  if (selidx) arow = ((arow >> 9) * TT) + selidx[m0 + r];
  const ushort* ga = A + (size_t)arow * K + seg * 16;
  const ushort* gb = Bt + (size_t)(n0 + r) * K + seg * 16;

  f32x4 acc[4][4];
#pragma unroll
  for (int i = 0; i < 4; ++i)
#pragma unroll
    for (int j = 0; j < 4; ++j) acc[i][j] = (f32x4){0.f, 0.f, 0.f, 0.f};

  int nk = K >> 5;
  us8 apre0 = *(const us8*)ga, apre1 = *(const us8*)(ga + 8);
  us8 bpre0 = *(const us8*)gb, bpre1 = *(const us8*)(gb + 8);
  for (int kk = 0; kk < nk; ++kk) {
    __syncthreads();
    *(us8*)(As + r * 40 + seg * 16) = apre0;
    *(us8*)(As + r * 40 + seg * 16 + 8) = apre1;
    *(us8*)(Bs + r * 40 + seg * 16) = bpre0;
    *(us8*)(Bs + r * 40 + seg * 16 + 8) = bpre1;
    __syncthreads();
    if (kk + 1 < nk) {
      apre0 = *(const us8*)(ga + (kk + 1) * 32);
      apre1 = *(const us8*)(ga + (kk + 1) * 32 + 8);
      bpre0 = *(const us8*)(gb + (kk + 1) * 32);
      bpre1 = *(const us8*)(gb + (kk + 1) * 32 + 8);
    }
    bf16x8 af[4], bf[4];
#pragma unroll
    for (int mf = 0; mf < 4; ++mf)
      af[mf] = *(const bf16x8*)(As + (wm * 64 + mf * 16 + l15) * 40 + quad * 8);
#pragma unroll
    for (int nf = 0; nf < 4; ++nf)
      bf[nf] = *(const bf16x8*)(Bs + (wn * 64 + nf * 16 + l15) * 40 + quad * 8);
#pragma unroll
    for (int mf = 0; mf < 4; ++mf)
#pragma unroll
      for (int nf = 0; nf < 4; ++nf)
        acc[mf][nf] = __builtin_amdgcn_mfma_f32_16x16x32_bf16(af[mf], bf[nf], acc[mf][nf], 0, 0, 0);
  }

  if (ropemode && blockIdx.y >= 4) {
    // rope pairs: cols (c, c+32) live in frags (nf, nf+2), nf in {0,1}
#pragma unroll
    for (int mf = 0; mf < 4; ++mf) {
#pragma unroll
      for (int nf = 0; nf < 2; ++nf) {
        int dd = nf * 16 + l15;
#pragma unroll
        for (int reg = 0; reg < 4; ++reg) {
          int row = m0 + wm * 64 + mf * 16 + quad * 4 + reg;
          int t = row & (TT - 1);
          float c = cosp[t * 32 + dd], s = sinp[t * 32 + dd];
          float xr = acc[mf][nf][reg], xi = acc[mf][nf + 2][reg];
          int col = n0 + wn * 64 + nf * 16 + l15;
          size_t oi = (size_t)row * ldo + col;
          ((ushort*)Out)[oi] = (ushort)f2bf(xr * c - xi * s);
          ((ushort*)Out)[oi + 32] = (ushort)f2bf(xr * s + xi * c);
        }
      }
    }
    return;
  }
#pragma unroll
  for (int mf = 0; mf < 4; ++mf) {
#pragma unroll
    for (int nf = 0; nf < 4; ++nf) {
#pragma unroll
      for (int reg = 0; reg < 4; ++reg) {
        int row = m0 + wm * 64 + mf * 16 + quad * 4 + reg;
        int col = n0 + wn * 64 + nf * 16 + l15;
        size_t oi = (size_t)row * ldo + col;
        float v = acc[mf][nf][reg];
        if (obf16) ((ushort*)Out)[oi] = (ushort)f2bf(v);
        else ((float*)Out)[oi] = v;
      }
    }
  }
}

// ---------------- merged norm/postproc ----------------
// blocks 0..4095: nkv row postproc (rmsnorm, kr-rope, f32 imp score)
// blocks 4096..8191: nq rmsnorm
__global__ __launch_bounds__(128) void norm_kernel(const float* __restrict__ nkvraw,
                                                   const float* __restrict__ nqraw,
                                                   const float* __restrict__ x,
                                                   const float* __restrict__ W_imp,
                                                   const float* __restrict__ b_imp,
                                                   const float* __restrict__ kvnw,
                                                   const float* __restrict__ qnw,
                                                   const float* __restrict__ cos_t,
                                                   const float* __restrict__ sin_t,
                                                   ushort* __restrict__ nkvb,
                                                   ushort* __restrict__ krbf,
                                                   float* __restrict__ scores,
                                                   ushort* __restrict__ nqb) {
  int tid = threadIdx.x;
  if (blockIdx.x < 4096) {
    int row = blockIdx.x;
    int t = row & (TT - 1);
    if (tid < 32) {
      float v = nkvraw[(size_t)row * 128 + tid];
      float ss = v * v;
#pragma unroll
      for (int off = 16; off > 0; off >>= 1) ss += __shfl_xor(ss, off, 32);
      nkvb[(size_t)row * 32 + tid] = (ushort)f2bf(v * rsqrtf(ss / 32.f + 1e-6f) * kvnw[tid]);
    } else if (tid < 64) {
      int dd = tid - 32;
      float xr = nkvraw[(size_t)row * 128 + 32 + dd];
      float xi = nkvraw[(size_t)row * 128 + 64 + dd];
      float c = cos_t[t * 32 + dd], s = sin_t[t * 32 + dd];
      krbf[(size_t)row * 64 + dd] = (ushort)f2bf(xr * c - xi * s);
      krbf[(size_t)row * 64 + dd + 32] = (ushort)f2bf(xr * s + xi * c);
    } else {
      int lane = tid - 64;  // wave 1, full 64 lanes
      float p = 0.f;
#pragma unroll
      for (int k = 0; k < 4; ++k) p += x[(size_t)row * 256 + lane + k * 64] * W_imp[lane + k * 64];
#pragma unroll
      for (int off = 32; off > 0; off >>= 1) p += __shfl_down(p, off, 64);
      if (lane == 0) scores[row] = p + b_imp[0];
    }
  } else {
    int row = blockIdx.x - 4096;
    __shared__ float red2[2];
    float v = (tid < 96) ? nqraw[(size_t)row * 128 + tid] : 0.f;
    float p = v * v;
#pragma unroll
    for (int off = 32; off > 0; off >>= 1) p += __shfl_down(p, off, 64);
    if ((tid & 63) == 0) red2[tid >> 6] = p;
    __syncthreads();
    float ss = red2[0] + red2[1];
    float sc = rsqrtf(ss / 96.f + 1e-6f);
    if (tid < 96) nqb[(size_t)row * 96 + tid] = (ushort)f2bf(v * sc * qnw[tid]);
  }
}

// ---------------- gate finalize (reads nkvraw cols 96..98, stride 128) ----------------
__global__ __launch_bounds__(256) void gate_kernel(const float* __restrict__ nkvraw,
                                                   const float* __restrict__ b_gate,
                                                   float* __restrict__ bw) {
  int tid = threadIdx.x;  // 256
  float a0 = 0, a1 = 0, a2 = 0, a3 = 0, a4 = 0, a5 = 0;
  for (int r = tid; r < 2 * TT; r += 256) {
    float g0 = nkvraw[(size_t)r * 128 + 96];
    float g1 = nkvraw[(size_t)r * 128 + 97];
    float g2 = nkvraw[(size_t)r * 128 + 98];
    if (r < TT) { a0 += g0; a1 += g1; a2 += g2; }
    else { a3 += g0; a4 += g1; a5 += g2; }
  }
  __shared__ float red[6][256];
  red[0][tid] = a0; red[1][tid] = a1; red[2][tid] = a2;
  red[3][tid] = a3; red[4][tid] = a4; red[5][tid] = a5;
  __syncthreads();
  for (int s = 128; s > 0; s >>= 1) {
    if (tid < s) {
#pragma unroll
      for (int q = 0; q < 6; ++q) red[q][tid] += red[q][tid + s];
    }
    __syncthreads();
  }
  if (tid == 0) {
    for (int b = 0; b < 2; ++b) {
      float v[3];
      float mx = -INFINITY;
      for (int j = 0; j < 3; ++j) {
        v[j] = red[b * 3 + j][0] / (float)TT + b_gate[j];
        mx = fmaxf(mx, v[j]);
      }
      float sum = 0.f;
      for (int j = 0; j < 3; ++j) { v[j] = expf(v[j] - mx); sum += v[j]; }
      for (int j = 0; j < 3; ++j) bw[b * 3 + j] = v[j] / sum;
    }
  }
}

// ---------------- top-k stage 1: ranks -> flags ----------------
__global__ __launch_bounds__(1024) void topk_rank_kernel(const float* __restrict__ scores,
                                                         int* __restrict__ flags) {
  int b = blockIdx.y, blk = blockIdx.x;
  int tid = threadIdx.x;
  __shared__ unsigned sk[TT];
#pragma unroll
  for (int e = 0; e < 2; ++e) {
    int i = tid + e * 1024;
    float s = scores[b * TT + i];
    unsigned u = __float_as_uint(s);
    u = (u & 0x80000000u) ? ~u : (u | 0x80000000u);
    sk[i] = u;
  }
  __syncthreads();
  int e = blk * 64 + (tid >> 4);
  int sub = tid & 15;
  unsigned u = sk[e];
  int r = 0;
  int j0 = sub * 128;
#pragma unroll 8
  for (int j = j0; j < j0 + 128; ++j) {
    unsigned v = sk[j];
    r += (int)((v > u) || (v == u && j < e));
  }
#pragma unroll
  for (int off = 8; off > 0; off >>= 1) r += __shfl_down(r, off, 16);
  if (sub == 0) flags[b * TT + e] = (r < 512) ? 1 : 0;
}

// ---------------- top-k stage 2: scan + scatter ----------------
__global__ __launch_bounds__(1024) void topk_scan_kernel(const int* __restrict__ flags,
                                                         int* __restrict__ selidx) {
  int b = blockIdx.x, tid = threadIdx.x;
  __shared__ int pre[TT];
  int f0 = flags[b * TT + tid], f1 = flags[b * TT + tid + 1024];
  pre[tid] = f0;
  pre[tid + 1024] = f1;
  __syncthreads();
  for (int off = 1; off < TT; off <<= 1) {
    int a0 = (tid >= off) ? pre[tid - off] : 0;
    int a1 = (tid + 1024 >= off) ? pre[tid + 1024 - off] : 0;
    __syncthreads();
    pre[tid] += a0;
    pre[tid + 1024] += a1;
    __syncthreads();
  }
  if (f0) selidx[b * 512 + pre[tid] - 1] = tid;
  if (f1) selidx[b * 512 + pre[tid + 1024] - 1] = tid + 1024;
}

// ---------------- fused flash attention, 32x32x16 MFMA, S^T formulation ----------------
// Block = 128 Q-rows x (cmp+sel+win). Wave wv owns q rows wv*32..+31.
// S^T = K·Q^T (C: col=q in lanes, row=key in regs) -> P packed b64 to Ps[q][key]
// -> O = P·V with clean b128 A/B frags. l in-register + 1 shuffle.
__global__ __launch_bounds__(256) void flash_fused_kernel(
    const ushort* __restrict__ qbf,    // [row][qn 512 | qr 1024] bf16, scale folded
    const ushort* __restrict__ kv,     // [row][kn 512 | v 512] bf16
    const ushort* __restrict__ krbf,   // [row][64] bf16 (roped)
    const ushort* __restrict__ selt,   // [selrow][sk 1536 | sv 512] bf16
    const ushort* __restrict__ wint,   // [row][wk 1536 | wv 512] bf16
    const float* __restrict__ bw,
    ushort* __restrict__ attout) {     // [b*TT+t][h*32+d] bf16
  __shared__ __align__(16) short Qs[128 * 104];
  __shared__ __align__(16) short Ks[64 * 104];
  __shared__ __align__(16) short Vts[32 * 72];
  __shared__ __align__(16) short Ps[128 * 72];
  __shared__ float Ls[4][32];

  int bx = blockIdx.x;
  int j = bx >> 5;  // 0..15
  // pairing: blocks i and i+256 land on same CU; qtile(j)+qtile(j+8)=15 (balanced)
  int qtile = (j < 8) ? (15 - 2 * j) : (2 * (j - 8));
  int bh = bx & 31;
  int b = bh >> 4, h = bh & 15;
  int tid = threadIdx.x;
  int wv = tid >> 6, lane = tid & 63;
  int l31 = lane & 31, half = lane >> 5;

  int qrow0 = qtile * 128;
  for (int i = tid; i < 128 * 24; i += 256) {
    int qi = i / 24, dp = (i - qi * 24) * 4;
    int col = (dp < 32) ? (h * 32 + dp) : (512 + h * 64 + (dp - 32));
    *(ushort4*)(Qs + qi * 104 + dp) =
        *(const ushort4*)(qbf + (size_t)(b * TT + qrow0 + qi) * 1536 + col);
  }

  f32x16 oacc;
#pragma unroll
  for (int r = 0; r < 16; ++r) oacc[r] = 0.f;

  ushort4 kpre[6];
  ushort2 vpa[2], vpb[2];

  for (int s = 0; s < 3; ++s) {
    const ushort *kb1, *kb2, *vb;
    size_t krs1, krs2, vrs;
    int split, Tk, causal;
    if (s == 0) {  // cmp
      kb1 = kv + h * 32;        krs1 = 1024; split = 32;
      kb2 = krbf;               krs2 = 64;
      vb = kv + 512 + h * 32;   vrs = 1024;
      Tk = TT; causal = 1;
    } else if (s == 1) {  // sel
      kb1 = selt + h * 96;      krs1 = 2048; split = 96;
      kb2 = selt;               krs2 = 2048;
      vb = selt + 1536 + h * 32; vrs = 2048;
      Tk = 512; causal = 0;
    } else {  // win
      kb1 = wint + h * 96;      krs1 = 2048; split = 96;
      kb2 = wint;               krs2 = 2048;
      vb = wint + 1536 + h * 32; vrs = 2048;
      Tk = TT; causal = 1;
    }
    size_t bTk = (size_t)b * Tk;

    auto prefetch = [&](int kt) {
      int krow0 = kt * 64;
#pragma unroll
      for (int c = 0; c < 6; ++c) {
        int i = c * 256 + tid;
        int kj = i / 24, dp = (i - kj * 24) * 4;
        const ushort* src = (dp < split)
                                ? kb1 + (bTk + krow0 + kj) * krs1 + dp
                                : kb2 + (bTk + krow0 + kj) * krs2 + (dp - split);
        kpre[c] = *(const ushort4*)src;
      }
#pragma unroll
      for (int c = 0; c < 2; ++c) {
        int i = c * 256 + tid;
        int d0 = (i & 15) * 2, kjp = (i >> 4) * 2;
        vpa[c] = *(const ushort2*)(vb + (bTk + krow0 + kjp) * vrs + d0);
        vpb[c] = *(const ushort2*)(vb + (bTk + krow0 + kjp + 1) * vrs + d0);
      }
    };
    auto commit = [&]() {
#pragma unroll
      for (int c = 0; c < 6; ++c) {
        int i = c * 256 + tid;
        int kj = i / 24, dp = (i - kj * 24) * 4;
        *(ushort4*)(Ks + kj * 104 + dp) = kpre[c];
      }
#pragma unroll
      for (int c = 0; c < 2; ++c) {
        int i = c * 256 + tid;
        int d0 = (i & 15) * 2, kjp = (i >> 4) * 2;
        *(unsigned*)(Vts + (d0 + 0) * 72 + kjp) =
            (unsigned)vpa[c].x | ((unsigned)vpb[c].x << 16);
        *(unsigned*)(Vts + (d0 + 1) * 72 + kjp) =
            (unsigned)vpa[c].y | ((unsigned)vpb[c].y << 16);
      }
    };

    f32x16 of;
#pragma unroll
    for (int r = 0; r < 16; ++r) of[r] = 0.f;
    float lsum = 0.f;

    int nkt = causal ? (2 * qtile + 2) : 8;
    prefetch(0);
    for (int kt = 0; kt < nkt; ++kt) {
      __syncthreads();
      commit();
      __syncthreads();
      if (kt + 1 < nkt) prefetch(kt + 1);
      int krow0 = kt * 64;

      // ---- S^T = K · Q^T ----
      f32x16 sfT[2];
#pragma unroll
      for (int r = 0; r < 16; ++r) { sfT[0][r] = 0.f; sfT[1][r] = 0.f; }
#pragma unroll
      for (int ks = 0; ks < 6; ++ks) {
        bf16x8 bq = *(const bf16x8*)(Qs + (wv * 32 + l31) * 104 + ks * 16 + half * 8);
#pragma unroll
        for (int kb = 0; kb < 2; ++kb) {
          bf16x8 ak = *(const bf16x8*)(Ks + (kb * 32 + l31) * 104 + ks * 16 + half * 8);
          sfT[kb] = __builtin_amdgcn_mfma_f32_32x32x16_bf16(ak, bq, sfT[kb], 0, 0, 0);
        }
      }
      // C-layout: col=lane&31=q_local, row=key_local=(reg&3)+8*(reg>>2)+4*half
      int qg = qrow0 + wv * 32 + l31;
      int domask = causal && (kt >= 2 * qtile);
      short* Pw = Ps + (wv * 32 + l31) * 72;
#pragma unroll
      for (int kb = 0; kb < 2; ++kb) {
#pragma unroll
        for (int g = 0; g < 4; ++g) {
          ushort4 w;
          float p0, p1, p2, p3;
          {
            int key0 = krow0 + kb * 32 + 8 * g + 4 * half;
            float s0 = sfT[kb][g * 4 + 0];
            float s1 = sfT[kb][g * 4 + 1];
            float s2 = sfT[kb][g * 4 + 2];
            float s3 = sfT[kb][g * 4 + 3];
            if (domask) {
              if (key0 + 0 > qg) s0 = -INFINITY;
              if (key0 + 1 > qg) s1 = -INFINITY;
              if (key0 + 2 > qg) s2 = -INFINITY;
              if (key0 + 3 > qg) s3 = -INFINITY;
            }
            p0 = __expf(fminf(s0, 30.f));
            p1 = __expf(fminf(s1, 30.f));
            p2 = __expf(fminf(s2, 30.f));
            p3 = __expf(fminf(s3, 30.f));
          }
          lsum += p0 + p1 + p2 + p3;
          w.x = (ushort)f2bf(p0); w.y = (ushort)f2bf(p1);
          w.z = (ushort)f2bf(p2); w.w = (ushort)f2bf(p3);
          *(ushort4*)(Pw + kb * 32 + 8 * g + 4 * half) = w;
        }
      }
      // Ps is wave-private: in-wave LDS ordering only
      asm volatile("s_waitcnt lgkmcnt(0)" ::: "memory");

      // ---- O += P · V ----
#pragma unroll
      for (int ks2 = 0; ks2 < 4; ++ks2) {
        bf16x8 ap = *(const bf16x8*)(Ps + (wv * 32 + l31) * 72 + ks2 * 16 + half * 8);
        bf16x8 bv = *(const bf16x8*)(Vts + l31 * 72 + ks2 * 16 + half * 8);
        of = __builtin_amdgcn_mfma_f32_32x32x16_bf16(ap, bv, of, 0, 0, 0);
      }
    }

    lsum += __shfl_xor(lsum, 32, 64);
    if (half == 0) Ls[wv][l31] = lsum;
    asm volatile("s_waitcnt lgkmcnt(0)" ::: "memory");
    float wgt = bw[b * 3 + s];
#pragma unroll
    for (int reg = 0; reg < 16; ++reg) {
      int ql = (reg & 3) + 8 * (reg >> 2) + 4 * half;
      oacc[reg] += of[reg] * (wgt / Ls[wv][ql]);
    }
  }

  // epilogue: O C-layout col=lane&31=dv, row=q_local
#pragma unroll
  for (int reg = 0; reg < 16; ++reg) {
    int trow = qrow0 + wv * 32 + (reg & 3) + 8 * (reg >> 2) + 4 * half;
    attout[(size_t)(b * TT + trow) * 512 + h * 32 + l31] = (ushort)f2bf(oacc[reg]);
  }
}

// ---------------- launch ----------------
extern "C" void kernel_launch(void* const* d_in, const int* in_sizes, int n_in,
                              void* d_out, int out_size, void* d_ws, size_t ws_size,
                              hipStream_t stream) {
  const float* x      = (const float*)d_in[0];
  const float* W_cq   = (const float*)d_in[1];
  const float* qnw    = (const float*)d_in[2];
  const float* W_dqn  = (const float*)d_in[3];
  const float* W_dqr  = (const float*)d_in[4];
  const float* W_ckv  = (const float*)d_in[5];
  const float* kvnw   = (const float*)d_in[6];
  const float* W_dkn  = (const float*)d_in[7];
  const float* W_dv   = (const float*)d_in[8];
  const float* W_kr   = (const float*)d_in[9];
  const float* W_imp  = (const float*)d_in[10];
  const float* b_imp  = (const float*)d_in[11];
  const float* W_selk = (const float*)d_in[12];
  const float* W_selv = (const float*)d_in[13];
  const float* W_wink = (const float*)d_in[14];
  const float* W_winv = (const float*)d_in[15];
  const float* W_gate = (const float*)d_in[16];
  const float* b_gate = (const float*)d_in[17];
  const float* W_proj = (const float*)d_in[18];
  const float* cos_f  = (const float*)d_in[19];
  const float* sin_f  = (const float*)d_in[20];
  float* out = (float*)d_out;
  float* ws  = (float*)d_ws;

  size_t off = 0;
  auto alloc = [&](size_t n) {
    float* p = ws + off;
    off += (n + 255) & ~(size_t)255;
    return p;
  };
  const int ROWS = 2 * TT;  // 4096
  ushort* xbf     = (ushort*)alloc((size_t)ROWS * 128);
  ushort* xhb     = (ushort*)alloc((size_t)ROWS * 128);
  float* nqraw    = alloc((size_t)ROWS * 128);
  float* nkvraw   = alloc((size_t)ROWS * 128);
  ushort* nqb     = (ushort*)alloc((size_t)ROWS * 48);
  ushort* qbf     = (ushort*)alloc((size_t)ROWS * 768);   // [qn 512 | qr 1024] bf16
  ushort* nkvb    = (ushort*)alloc((size_t)ROWS * 16);
  ushort* kvtmp   = (ushort*)alloc((size_t)ROWS * 512);   // [kn 512 | v 512] bf16
  ushort* krbf    = (ushort*)alloc((size_t)ROWS * 32);
  float* scores   = alloc(ROWS);
  float* bwp      = alloc(8);
  int* selidx     = (int*)alloc(1024);
  int* selflags   = (int*)alloc(ROWS);
  ushort* seltmp  = (ushort*)alloc((size_t)1024 * 1024);  // [sk|sv] bf16
  ushort* wintmp  = (ushort*)alloc((size_t)ROWS * 1024);  // [wk|wv] bf16
  ushort* attoutb = (ushort*)alloc((size_t)ROWS * 256);   // [4096][512] bf16
  ushort* Wt_q    = (ushort*)alloc((size_t)1536 * 48);
  ushort* Wt_kv   = (ushort*)alloc((size_t)1024 * 16);
  ushort* Wt_sel  = (ushort*)alloc((size_t)2048 * 128);
  ushort* Wt_win  = (ushort*)alloc((size_t)2048 * 128);
  ushort* Wt_proj = (ushort*)alloc((size_t)256 * 256);
  ushort* Wt_cq   = (ushort*)alloc((size_t)128 * 128);
  ushort* Wt_nkv  = (ushort*)alloc((size_t)128 * 128);

  wtconv_all_kernel<<<5568, 256, 0, stream>>>(
      W_dqn, W_dqr, W_dkn, W_dv, W_selk, W_selv, W_wink, W_winv, W_proj,
      W_cq, W_ckv, W_kr, W_gate, W_imp,
      Wt_q, Wt_kv, Wt_sel, Wt_win, Wt_proj, Wt_cq, Wt_nkv);

  logmap_kernel<<<ROWS, 256, 0, stream>>>(x, xhb, xbf);

  // front GEMMs (z=0: xh@W_cq -> nqraw; z=1: x@W_nkv -> nkvraw), f32 out ldo=128
  gemm_kernel<<<dim3(32, 1, 2), 256, 0, stream>>>(xhb, Wt_cq, nqraw, xbf, Wt_nkv, nkvraw,
                                                  nullptr, nullptr, nullptr, 256, 128, 0, 0);
  norm_kernel<<<2 * ROWS, 128, 0, stream>>>(nkvraw, nqraw, x, W_imp, b_imp, kvnw, qnw,
                                            cos_f, sin_f, nkvb, krbf, scores, nqb);
  // Q projection with fused rope (bf16 out)
  gemm_kernel<<<dim3(32, 12), 256, 0, stream>>>(nqb, Wt_q, qbf, nullptr, nullptr, nullptr,
                                                nullptr, cos_f, sin_f, 96, 1536, 1, 1);
  gemm_kernel<<<dim3(32, 8), 256, 0, stream>>>(nkvb, Wt_kv, kvtmp, nullptr, nullptr, nullptr,
                                               nullptr, nullptr, nullptr, 32, 1024, 1, 0);
  gate_kernel<<<1, 256, 0, stream>>>(nkvraw, b_gate, bwp);
  topk_rank_kernel<<<dim3(32, 2), 1024, 0, stream>>>(scores, selflags);
  topk_scan_kernel<<<2, 1024, 0, stream>>>(selflags, selidx);
  gemm_kernel<<<dim3(8, 16), 256, 0, stream>>>(xbf, Wt_sel, seltmp, nullptr, nullptr, nullptr,
                                               selidx, nullptr, nullptr, 256, 2048, 1, 0);
  gemm_kernel<<<dim3(32, 16), 256, 0, stream>>>(xbf, Wt_win, wintmp, nullptr, nullptr, nullptr,
                                                nullptr, nullptr, nullptr, 256, 2048, 1, 0);

  flash_fused_kernel<<<512, 256, 0, stream>>>(qbf, kvtmp, krbf, seltmp, wintmp, bwp, attoutb);

  gemm_kernel<<<dim3(32, 2), 256, 0, stream>>>(attoutb, Wt_proj, out, nullptr, nullptr, nullptr,
                                               nullptr, nullptr, nullptr, 512, 256, 0, 0);
}